// Round 4
// baseline (309.048 us; speedup 1.0000x reference)
//
#include <hip/hip_runtime.h>

#define NCLS 10
#define NUM_IMG 65536

// Async global->LDS, 16B per lane. LDS dest must be wave-uniform base + lane*16.
__device__ __forceinline__ void async_cp16(const float* g, float* l) {
    __builtin_amdgcn_global_load_lds(
        (const __attribute__((address_space(1))) void*)(g),
        (__attribute__((address_space(3))) void*)(l),
        16, 0, 0);
}

// Block = 448 threads (7 waves) over 64 images.
// STAGING (coalesced): row-pair rr of all 64 images = 896 float4 chunks
// (image i, chunk k=0..13). Thread t stages slots s=t and s=t+448 where
// slot s -> image s/14, chunk s%14. Consecutive lanes hit (mostly)
// consecutive 16-B chunks -> ~12 cache lines per wave-instr instead of 64.
// LDS layout [img][14] float4 (packed) is exactly lane-contiguous, as
// global_load_lds requires.
// COMPUTE (same as R3): lane = image, wave w handles patch-cols 2w,2w+1
// (top = chunk w, bottom = chunk w+7), W indices wave-uniform -> scalar.
__global__ __launch_bounds__(448, 7) void quanv_logits_kernel(
    const float* __restrict__ x,    // (B,1,28,28)
    const float* __restrict__ W,    // (10, 784)
    const float* __restrict__ bias, // (10,)
    float* __restrict__ out)        // (B, 10)
{
    __shared__ float4 sb[2][896];   // two 14336-B row-pair buffers (28672 B)

    const int tid  = threadIdx.x;
    const int w    = __builtin_amdgcn_readfirstlane(tid >> 6); // 0..6 uniform
    const int lane = tid & 63;                                  // image in block
    const int img0 = blockIdx.x << 6;

    // Per-thread staging pointers (row-pair rr adds rr*56 floats).
    const int s0 = tid, s1 = tid + 448;
    const float* g0 = x + (size_t)(img0 + s0 / 14) * 784 + (s0 % 14) * 4;
    const float* g1 = x + (size_t)(img0 + s1 / 14) * 784 + (s1 % 14) * 4;

    float acc[NCLS];
#pragma unroll
    for (int c = 0; c < NCLS; ++c) acc[c] = 0.0f;

    // Prologue: stage rr=0 into buffer 0
    async_cp16(g0, (float*)&sb[0][s0]);
    async_cp16(g1, (float*)&sb[0][s1]);
    __syncthreads();

#pragma unroll
    for (int rr = 0; rr < 14; ++rr) {
        const int cur = rr & 1, nxt = cur ^ 1;
        if (rr < 13) {  // prefetch next row-pair (fire-and-forget)
            async_cp16(g0 + (rr + 1) * 56, (float*)&sb[nxt][s0]);
            async_cp16(g1 + (rr + 1) * 56, (float*)&sb[nxt][s1]);
        }

        const float4 t4 = sb[cur][lane * 14 + w];      // top row, cols 4w..4w+3
        const float4 b4 = sb[cur][lane * 14 + w + 7];  // bottom row

        // patch j=2w: cumprod(cos) over (tl, tr, bl, br)
        const float e0 = __cosf(t4.x);
        const float e1 = e0 * __cosf(t4.y);
        const float e2 = e1 * __cosf(b4.x);
        const float e3 = e2 * __cosf(b4.y);
        // patch j=2w+1
        const float f0 = __cosf(t4.z);
        const float f1 = f0 * __cosf(t4.w);
        const float f2 = f1 * __cosf(b4.z);
        const float f3 = f2 * __cosf(b4.w);

        const int P = (rr * 14 + 2 * w) * 4;  // uniform -> scalar W loads
#pragma unroll
        for (int c = 0; c < NCLS; ++c) {
            const float4 wa = *reinterpret_cast<const float4*>(&W[c * 784 + P]);
            const float4 wb = *reinterpret_cast<const float4*>(&W[c * 784 + P + 4]);
            float a = acc[c];
            a = fmaf(e0, wa.x, a); a = fmaf(e1, wa.y, a);
            a = fmaf(e2, wa.z, a); a = fmaf(e3, wa.w, a);
            a = fmaf(f0, wb.x, a); a = fmaf(f1, wb.y, a);
            a = fmaf(f2, wb.z, a); a = fmaf(f3, wb.w, a);
            acc[c] = a;
        }
        // Barrier: (a) buf[cur] reads done before restage; (b) each wave's
        // vmcnt drained -> buf[nxt] complete for all after the barrier.
        __syncthreads();
    }

    // Reduce 7 per-wave partials. Reuse sb; stride 71 floats (odd -> no conflict).
    float* part = (float*)sb;
#pragma unroll
    for (int c = 0; c < NCLS; ++c) part[lane * 71 + w * NCLS + c] = acc[c];
    __syncthreads();

    if (w == 0) {
        float s[NCLS];
#pragma unroll
        for (int c = 0; c < NCLS; ++c) s[c] = bias[c];
        for (int ww = 0; ww < 7; ++ww) {
#pragma unroll
            for (int c = 0; c < NCLS; ++c) s[c] += part[lane * 71 + ww * NCLS + c];
        }
        float m = s[0];
#pragma unroll
        for (int c = 1; c < NCLS; ++c) m = fmaxf(m, s[c]);
        float sum = 0.0f;
#pragma unroll
        for (int c = 0; c < NCLS; ++c) sum += __expf(s[c] - m);
        const float lse = __logf(sum) + m;

        float* o = out + (size_t)(img0 + lane) * NCLS;
#pragma unroll
        for (int c = 0; c < NCLS; c += 2) {
            float2 v;
            v.x = s[c]     - lse;
            v.y = s[c + 1] - lse;
            *reinterpret_cast<float2*>(o + c) = v;
        }
    }
}

extern "C" void kernel_launch(void* const* d_in, const int* in_sizes, int n_in,
                              void* d_out, int out_size, void* d_ws, size_t ws_size,
                              hipStream_t stream) {
    const float* x    = (const float*)d_in[0];
    const float* W    = (const float*)d_in[1];
    const float* bias = (const float*)d_in[2];
    float* out        = (float*)d_out;

    dim3 block(448);               // 7 waves
    dim3 grid(NUM_IMG / 64);       // 1024 blocks, 64 images each
    quanv_logits_kernel<<<grid, block, 0, stream>>>(x, W, bias, out);
}

// Round 5
// 290.975 us; speedup vs baseline: 1.0621x; 1.0621x over previous
//
#include <hip/hip_runtime.h>

#define NCLS 10
#define NUM_IMG 65536

// Async global->LDS, 16B per lane. LDS dest must be wave-uniform base + lane*16.
__device__ __forceinline__ void async_cp16(const float* g, float* l) {
    __builtin_amdgcn_global_load_lds(
        (const __attribute__((address_space(1))) void*)(g),
        (__attribute__((address_space(3))) void*)(l),
        16, 0, 0);
}

// R5 = R4 with ONE change: W is staged into LDS once per block and read via
// same-address broadcast ds_read_b128 (conflict-free), replacing the
// s_load_dwordx4 scalar path that thrashes the shared constant cache.
// Everything else (coalesced global_load_lds staging of x, double buffer,
// 7-wave patch split, barrier cadence) is identical to R4.
__global__ __launch_bounds__(448, 4) void quanv_logits_kernel(
    const float* __restrict__ x,    // (B,1,28,28)
    const float* __restrict__ W,    // (10, 784)
    const float* __restrict__ bias, // (10,)
    float* __restrict__ out)        // (B, 10)
{
    __shared__ float4 sb[2][896];   // x row-pair double buffer (28672 B)
    __shared__ float  sW[7840];     // W, row-major 10x784 (31360 B)

    const int tid  = threadIdx.x;
    const int w    = __builtin_amdgcn_readfirstlane(tid >> 6); // 0..6 uniform
    const int lane = tid & 63;                                  // image in block
    const int img0 = blockIdx.x << 6;

    // Stage W into LDS: 1960 float4, coalesced, once per block.
    {
        const float4* Wg = reinterpret_cast<const float4*>(W);
        float4* Wl = reinterpret_cast<float4*>(sW);
#pragma unroll
        for (int r = 0; r < 5; ++r) {
            const int idx = tid + r * 448;
            if (idx < 1960) Wl[idx] = Wg[idx];
        }
    }

    // Coalesced x staging: thread t owns float4-slots s=t, t+448 of each
    // row-pair tile; slot s -> image s/14, chunk s%14 ([img][14] packed LDS).
    const int s0 = tid, s1 = tid + 448;
    const float* g0 = x + (size_t)(img0 + s0 / 14) * 784 + (s0 % 14) * 4;
    const float* g1 = x + (size_t)(img0 + s1 / 14) * 784 + (s1 % 14) * 4;

    float acc[NCLS];
#pragma unroll
    for (int c = 0; c < NCLS; ++c) acc[c] = 0.0f;

    // Prologue: stage rr=0 into buffer 0 (barrier also publishes sW).
    async_cp16(g0, (float*)&sb[0][s0]);
    async_cp16(g1, (float*)&sb[0][s1]);
    __syncthreads();

#pragma unroll
    for (int rr = 0; rr < 14; ++rr) {
        const int cur = rr & 1, nxt = cur ^ 1;
        if (rr < 13) {  // prefetch next row-pair (fire-and-forget)
            async_cp16(g0 + (rr + 1) * 56, (float*)&sb[nxt][s0]);
            async_cp16(g1 + (rr + 1) * 56, (float*)&sb[nxt][s1]);
        }

        const float4 t4 = sb[cur][lane * 14 + w];      // top row, cols 4w..4w+3
        const float4 b4 = sb[cur][lane * 14 + w + 7];  // bottom row

        // patch j=2w: cumprod(cos) over (tl, tr, bl, br)
        const float e0 = __cosf(t4.x);
        const float e1 = e0 * __cosf(t4.y);
        const float e2 = e1 * __cosf(b4.x);
        const float e3 = e2 * __cosf(b4.y);
        // patch j=2w+1
        const float f0 = __cosf(t4.z);
        const float f1 = f0 * __cosf(t4.w);
        const float f2 = f1 * __cosf(b4.z);
        const float f3 = f2 * __cosf(b4.w);

        const int P = (rr * 14 + 2 * w) * 4;  // same for all lanes -> broadcast
#pragma unroll
        for (int c = 0; c < NCLS; ++c) {
            const float4 wa = *reinterpret_cast<const float4*>(&sW[c * 784 + P]);
            const float4 wb = *reinterpret_cast<const float4*>(&sW[c * 784 + P + 4]);
            float a = acc[c];
            a = fmaf(e0, wa.x, a); a = fmaf(e1, wa.y, a);
            a = fmaf(e2, wa.z, a); a = fmaf(e3, wa.w, a);
            a = fmaf(f0, wb.x, a); a = fmaf(f1, wb.y, a);
            a = fmaf(f2, wb.z, a); a = fmaf(f3, wb.w, a);
            acc[c] = a;
        }
        // Barrier: (a) buf[cur] reads done before restage; (b) each wave's
        // vmcnt drained -> buf[nxt] complete for all after the barrier.
        __syncthreads();
    }

    // Reduce 7 per-wave partials. Reuse sb; stride 71 floats (odd -> no conflict).
    float* part = (float*)sb;
#pragma unroll
    for (int c = 0; c < NCLS; ++c) part[lane * 71 + w * NCLS + c] = acc[c];
    __syncthreads();

    if (w == 0) {
        float s[NCLS];
#pragma unroll
        for (int c = 0; c < NCLS; ++c) s[c] = bias[c];
        for (int ww = 0; ww < 7; ++ww) {
#pragma unroll
            for (int c = 0; c < NCLS; ++c) s[c] += part[lane * 71 + ww * NCLS + c];
        }
        float m = s[0];
#pragma unroll
        for (int c = 1; c < NCLS; ++c) m = fmaxf(m, s[c]);
        float sum = 0.0f;
#pragma unroll
        for (int c = 0; c < NCLS; ++c) sum += __expf(s[c] - m);
        const float lse = __logf(sum) + m;

        float* o = out + (size_t)(img0 + lane) * NCLS;
#pragma unroll
        for (int c = 0; c < NCLS; c += 2) {
            float2 v;
            v.x = s[c]     - lse;
            v.y = s[c + 1] - lse;
            *reinterpret_cast<float2*>(o + c) = v;
        }
    }
}

extern "C" void kernel_launch(void* const* d_in, const int* in_sizes, int n_in,
                              void* d_out, int out_size, void* d_ws, size_t ws_size,
                              hipStream_t stream) {
    const float* x    = (const float*)d_in[0];
    const float* W    = (const float*)d_in[1];
    const float* bias = (const float*)d_in[2];
    float* out        = (float*)d_out;

    dim3 block(448);               // 7 waves
    dim3 grid(NUM_IMG / 64);       // 1024 blocks, 64 images each
    quanv_logits_kernel<<<grid, block, 0, stream>>>(x, W, bias, out);
}